// Round 2
// baseline (310.722 us; speedup 1.0000x reference)
//
#include <hip/hip_runtime.h>
#include <math.h>

#define NUM_CODES 128
#define CODE_DIM  64
#define B_ 64
#define D_ 64
#define T_ 8192
#define N_TOK (B_ * T_)   // 524288

// ---------------------------------------------------------------------------
// prep: half centroid squared norms + zero histogram
// ---------------------------------------------------------------------------
__global__ __launch_bounds__(128) void kmeans_prep(
    const float* __restrict__ centroids, float* __restrict__ c2h,
    unsigned int* __restrict__ counts)
{
    int k = threadIdx.x;
    if (k < NUM_CODES) {
        const float* cp = centroids + k * CODE_DIM;
        float s0 = 0.f, s1 = 0.f, s2 = 0.f, s3 = 0.f;
        #pragma unroll
        for (int d = 0; d < CODE_DIM; d += 4) {
            s0 = fmaf(cp[d + 0], cp[d + 0], s0);
            s1 = fmaf(cp[d + 1], cp[d + 1], s1);
            s2 = fmaf(cp[d + 2], cp[d + 2], s2);
            s3 = fmaf(cp[d + 3], cp[d + 3], s3);
        }
        c2h[k] = 0.5f * ((s0 + s1) + (s2 + s3));
        counts[k] = 0u;
    }
}

// ---------------------------------------------------------------------------
// assign: one thread per token. z column in VGPRs, centroids via uniform
// (scalar) loads -> inner loop is pure v_fmac_f32.
// argmin ||z-c||^2 == argmax (z.c - 0.5||c||^2); strict '>' keeps JAX's
// first-min tie-break.
// ---------------------------------------------------------------------------
__global__ __launch_bounds__(256) void kmeans_assign(
    const float* __restrict__ z_e, const float* __restrict__ centroids,
    const float* __restrict__ c2h, unsigned int* __restrict__ counts,
    float* __restrict__ out_idx)
{
    const int n = blockIdx.x * 256 + threadIdx.x;   // token id, n = b*T + t
    const int b = n >> 13;                          // / T_
    const int t = n & (T_ - 1);

    // z vector for token (b,t): z_e[b, d, t], stride T_ between d's.
    // Across a wave, consecutive t -> every load is a coalesced 256B txn.
    const float* zp = z_e + (size_t)b * (size_t)(D_ * T_) + t;
    float z[64];
    #pragma unroll
    for (int d = 0; d < 64; ++d) z[d] = zp[(size_t)d * T_];

    float best = -3.4e38f;
    int   bi   = 0;

    for (int k = 0; k < NUM_CODES; ++k) {
        const float* cp = centroids + k * CODE_DIM;  // uniform address -> SGPR loads
        float a0 = -c2h[k], a1 = 0.f, a2 = 0.f, a3 = 0.f;
        #pragma unroll
        for (int d = 0; d < 64; d += 4) {
            a0 = fmaf(cp[d + 0], z[d + 0], a0);
            a1 = fmaf(cp[d + 1], z[d + 1], a1);
            a2 = fmaf(cp[d + 2], z[d + 2], a2);
            a3 = fmaf(cp[d + 3], z[d + 3], a3);
        }
        float m = (a0 + a1) + (a2 + a3);             // z.c - 0.5||c||^2
        if (m > best) { best = m; bi = k; }          // first-max == first-min dist
    }

    out_idx[n] = (float)bi;

    // block histogram -> global atomics
    __shared__ unsigned int hist[NUM_CODES];
    if (threadIdx.x < NUM_CODES) hist[threadIdx.x] = 0u;
    __syncthreads();
    atomicAdd(&hist[bi], 1u);
    __syncthreads();
    if (threadIdx.x < NUM_CODES) {
        unsigned int h = hist[threadIdx.x];
        if (h) atomicAdd(&counts[threadIdx.x], h);
    }
}

// ---------------------------------------------------------------------------
// finalize: entropy -> perplexity, usage
// ---------------------------------------------------------------------------
__global__ __launch_bounds__(128) void kmeans_finalize(
    const unsigned int* __restrict__ counts, float* __restrict__ out)
{
    const int k = threadIdx.x;  // 0..127
    unsigned int c = counts[k];
    float p = fmaxf((float)c * (1.0f / (float)N_TOK), 1e-12f);
    float h = -p * logf(p);
    float u = (c > 0u) ? 1.0f : 0.0f;

    __shared__ float sh[NUM_CODES];
    __shared__ float su[NUM_CODES];
    sh[k] = h; su[k] = u;
    __syncthreads();
    for (int s = 64; s > 0; s >>= 1) {
        if (k < s) { sh[k] += sh[k + s]; su[k] += su[k + s]; }
        __syncthreads();
    }
    if (k == 0) {
        out[N_TOK + 0] = expf(sh[0]);            // perplexity
        out[N_TOK + 1] = su[0] * (1.0f / 128.f); // usage
    }
}

// ---------------------------------------------------------------------------
extern "C" void kernel_launch(void* const* d_in, const int* in_sizes, int n_in,
                              void* d_out, int out_size, void* d_ws, size_t ws_size,
                              hipStream_t stream)
{
    const float* z_e       = (const float*)d_in[0];
    const float* centroids = (const float*)d_in[1];
    float* out = (float*)d_out;

    float*        c2h    = (float*)d_ws;
    unsigned int* counts = (unsigned int*)d_ws + NUM_CODES;

    kmeans_prep<<<1, 128, 0, stream>>>(centroids, c2h, counts);
    kmeans_assign<<<N_TOK / 256, 256, 0, stream>>>(z_e, centroids, c2h, counts, out);
    kmeans_finalize<<<1, 128, 0, stream>>>(counts, out);
}

// Round 4
// 295.478 us; speedup vs baseline: 1.0516x; 1.0516x over previous
//
#include <hip/hip_runtime.h>
#include <math.h>

#define NUM_CODES 128
#define CODE_DIM  64
#define B_ 64
#define D_ 64
#define T_ 8192
#define N_TOK (B_ * T_)   // 524288

// ---------------------------------------------------------------------------
// prep: half centroid squared norms + zero histogram
// ---------------------------------------------------------------------------
__global__ __launch_bounds__(128) void kmeans_prep(
    const float* __restrict__ centroids, float* __restrict__ c2h,
    unsigned int* __restrict__ counts)
{
    int k = threadIdx.x;
    if (k < NUM_CODES) {
        const float* cp = centroids + k * CODE_DIM;
        float s0 = 0.f, s1 = 0.f, s2 = 0.f, s3 = 0.f;
        #pragma unroll
        for (int d = 0; d < CODE_DIM; d += 4) {
            s0 = fmaf(cp[d + 0], cp[d + 0], s0);
            s1 = fmaf(cp[d + 1], cp[d + 1], s1);
            s2 = fmaf(cp[d + 2], cp[d + 2], s2);
            s3 = fmaf(cp[d + 3], cp[d + 3], s3);
        }
        c2h[k] = 0.5f * ((s0 + s1) + (s2 + s3));
        counts[k] = 0u;
    }
}

// ---------------------------------------------------------------------------
// assign: TWO tokens per thread (adjacent t -> float2 loads). z stays in
// VGPRs (launch_bounds(256,2) -> 256-VGPR budget; ~150 used). Centroids via
// wave-uniform scalar loads. argmin||z-c||^2 == argmax(z.c - 0.5||c||^2);
// strict '>' keeps JAX first-min tie-break.
// ---------------------------------------------------------------------------
__global__ __launch_bounds__(256, 2) void kmeans_assign(
    const float* __restrict__ z_e, const float* __restrict__ centroids,
    const float* __restrict__ c2h, unsigned int* __restrict__ counts,
    float* __restrict__ out_idx)
{
    const int gtid = blockIdx.x * 256 + threadIdx.x;
    const int n0   = gtid * 2;                 // first token id (even)
    const int b    = n0 >> 13;                 // / T_
    const int t0   = n0 & (T_ - 1);            // even; t0+1 in same b

    // z columns for tokens (b,t0),(b,t0+1): z_e[b, d, t], d-stride T_.
    const float* zp = z_e + (size_t)b * (size_t)(D_ * T_) + t0;
    float za[64], zb[64];
    #pragma unroll
    for (int d = 0; d < 64; ++d) {
        float2 v = *(const float2*)(zp + (size_t)d * T_);
        za[d] = v.x; zb[d] = v.y;
    }

    float bestA = -3.4e38f, bestB = -3.4e38f;
    int   biA = 0, biB = 0;

    for (int k = 0; k < NUM_CODES; ++k) {
        const float* cp = centroids + k * CODE_DIM;  // wave-uniform -> s_load
        float nh = -c2h[k];
        float a0 = nh, a1 = 0.f, b0 = nh, b1 = 0.f;  // 4 indep FMA chains
        #pragma unroll
        for (int d = 0; d < 64; d += 2) {
            float c0 = cp[d], c1 = cp[d + 1];
            a0 = fmaf(c0, za[d],     a0);
            a1 = fmaf(c1, za[d + 1], a1);
            b0 = fmaf(c0, zb[d],     b0);
            b1 = fmaf(c1, zb[d + 1], b1);
        }
        float ma = a0 + a1, mb = b0 + b1;            // z.c - 0.5||c||^2
        if (ma > bestA) { bestA = ma; biA = k; }
        if (mb > bestB) { bestB = mb; biB = k; }
    }

    float2 o; o.x = (float)biA; o.y = (float)biB;
    *(float2*)(out_idx + n0) = o;

    // block histogram -> global atomics
    __shared__ unsigned int hist[NUM_CODES];
    if (threadIdx.x < NUM_CODES) hist[threadIdx.x] = 0u;
    __syncthreads();
    atomicAdd(&hist[biA], 1u);
    atomicAdd(&hist[biB], 1u);
    __syncthreads();
    if (threadIdx.x < NUM_CODES) {
        unsigned int h = hist[threadIdx.x];
        if (h) atomicAdd(&counts[threadIdx.x], h);
    }
}

// ---------------------------------------------------------------------------
// finalize: entropy -> perplexity, usage
// ---------------------------------------------------------------------------
__global__ __launch_bounds__(128) void kmeans_finalize(
    const unsigned int* __restrict__ counts, float* __restrict__ out)
{
    const int k = threadIdx.x;  // 0..127
    unsigned int c = counts[k];
    float p = fmaxf((float)c * (1.0f / (float)N_TOK), 1e-12f);
    float h = -p * logf(p);
    float u = (c > 0u) ? 1.0f : 0.0f;

    __shared__ float sh[NUM_CODES];
    __shared__ float su[NUM_CODES];
    sh[k] = h; su[k] = u;
    __syncthreads();
    for (int s = 64; s > 0; s >>= 1) {
        if (k < s) { sh[k] += sh[k + s]; su[k] += su[k + s]; }
        __syncthreads();
    }
    if (k == 0) {
        out[N_TOK + 0] = expf(sh[0]);            // perplexity
        out[N_TOK + 1] = su[0] * (1.0f / 128.f); // usage
    }
}

// ---------------------------------------------------------------------------
extern "C" void kernel_launch(void* const* d_in, const int* in_sizes, int n_in,
                              void* d_out, int out_size, void* d_ws, size_t ws_size,
                              hipStream_t stream)
{
    const float* z_e       = (const float*)d_in[0];
    const float* centroids = (const float*)d_in[1];
    float* out = (float*)d_out;

    float*        c2h    = (float*)d_ws;
    unsigned int* counts = (unsigned int*)d_ws + NUM_CODES;

    kmeans_prep<<<1, 128, 0, stream>>>(centroids, c2h, counts);
    kmeans_assign<<<N_TOK / 512, 256, 0, stream>>>(z_e, centroids, c2h, counts, out);
    kmeans_finalize<<<1, 128, 0, stream>>>(counts, out);
}